// Round 1
// baseline (13006.232 us; speedup 1.0000x reference)
//
#include <hip/hip_runtime.h>
#include <stdint.h>
#include <stddef.h>

// ---------------------------------------------------------------------------
// VRNN: B=128, T=512, F=128, H=256, Z=128
// Strategy:
//   PRE  (batched GEMMs over M=B*T):  x1 = x@phi_x + b          -> bf16
//                                     encx = x1@enc_h_w[:F]+b_e -> f32
//                                     lstmx = x1@lstm_k[:F]+b_l -> f32
//   SEQ  (8 WGs x 16 batch rows, T=512 loop, MFMA, only critical path):
//        enc_h -> enc_mu/enc_sigma -> z -> z1 -> gates -> (h,c)
//        writes enc_mu/enc_sigma/rnn_output to d_out, h_seq/z1_seq to ws
//   POST (batched GEMMs): prior_h->prior_mu/sigma, dec_h->dec_mu/sigma
// ---------------------------------------------------------------------------

typedef short s8v __attribute__((ext_vector_type(8)));   // 8 x bf16 bits
typedef float f4v __attribute__((ext_vector_type(4)));

__device__ __forceinline__ unsigned short f2b(float x) {
  union { float f; unsigned int u; } v; v.f = x;
  unsigned int r = ((v.u >> 16) & 1u) + 0x7fffu;
  return (unsigned short)((v.u + r) >> 16);
}
__device__ __forceinline__ float sigmoidf_(float x) { return 1.0f / (1.0f + __expf(-x)); }
__device__ __forceinline__ float tanh_(float x) { return 1.0f - 2.0f / (__expf(2.0f * x) + 1.0f); }
__device__ __forceinline__ float softplus_(float x) { return fmaxf(x, 0.0f) + log1pf(__expf(-fabsf(x))); }

// Pack a row-major [K,N] f32 weight matrix into bf16 MFMA-B-fragment layout:
// element (k,n) -> dst[ ((k>>3)*N + n)*8 + (k&7) ]
__global__ void pack_b_kernel(const float* __restrict__ src, unsigned short* __restrict__ dst,
                              int K, int N) {
  int idx = blockIdx.x * 256 + threadIdx.x;
  if (idx >= K * N) return;
  int k = idx / N, n = idx - k * N;
  dst[((((size_t)(k >> 3)) * N + n) << 3) + (k & 7)] = f2b(src[idx]);
}

// ---------------------------------------------------------------------------
// Generic tiled MFMA GEMM: C[M,N] = act( A1@B1 (+ A2@B2) + bias )
// A row-major (f32 or bf16-bits), B pre-packed fragment layout, M=65536.
// Block: 256 thr (4 waves). Tile 64x64: wave w -> rows 16w..16w+15, all 64 cols.
// ---------------------------------------------------------------------------
__launch_bounds__(256)
__global__ void gemm64_kernel(const void* __restrict__ A1, int a1_f32, int lda1,
                              const unsigned short* __restrict__ B1, int K1,
                              const void* __restrict__ A2, int lda2,
                              const unsigned short* __restrict__ B2, int K2,
                              const float* __restrict__ bias, int act,
                              float* __restrict__ outf, unsigned short* __restrict__ outb,
                              int N) {
  __shared__ unsigned short As[64][40];   // +8 pad: bank spread
  const int tid = threadIdx.x;
  const int wave = tid >> 6, lane = tid & 63, q = lane >> 4, l15 = lane & 15;
  const long m0 = (long)blockIdx.y * 64;
  const int n0 = blockIdx.x * 64;
  const int srow = tid >> 2, sc0 = (tid & 3) * 8;

  f4v acc[4];
#pragma unroll
  for (int i = 0; i < 4; ++i) acc[i] = (f4v){0.f, 0.f, 0.f, 0.f};

  for (int src = 0; src < 2; ++src) {
    const void* A = src ? A2 : A1;
    if (A == nullptr) continue;
    const unsigned short* Bp = src ? B2 : B1;
    const int K = src ? K2 : K1;
    const int lda = src ? lda2 : lda1;
    const int af32 = src ? 0 : a1_f32;
    const int nkc = K >> 5;
    for (int kc = 0; kc < nkc; ++kc) {
      // stage A[64,32] chunk into LDS as bf16
      {
        long aoff = (m0 + srow) * (long)lda + kc * 32 + sc0;
        if (af32) {
          const float* Ap = (const float*)A + aoff;
          float4 u0 = *(const float4*)(Ap);
          float4 u1 = *(const float4*)(Ap + 4);
          unsigned short* d = &As[srow][sc0];
          d[0] = f2b(u0.x); d[1] = f2b(u0.y); d[2] = f2b(u0.z); d[3] = f2b(u0.w);
          d[4] = f2b(u1.x); d[5] = f2b(u1.y); d[6] = f2b(u1.z); d[7] = f2b(u1.w);
        } else {
          const s8v* Ap = (const s8v*)((const unsigned short*)A + aoff);
          *(s8v*)&As[srow][sc0] = *Ap;
        }
      }
      __syncthreads();
      s8v a = *(const s8v*)&As[16 * wave + l15][q * 8];
#pragma unroll
      for (int nt = 0; nt < 4; ++nt) {
        const s8v b = *(const s8v*)(Bp + ((((long)kc * 4 + q) * N + n0 + nt * 16 + l15) << 3));
        acc[nt] = __builtin_amdgcn_mfma_f32_16x16x32_bf16(a, b, acc[nt], 0, 0, 0);
      }
      __syncthreads();
    }
  }
  // epilogue
#pragma unroll
  for (int nt = 0; nt < 4; ++nt) {
#pragma unroll
    for (int r = 0; r < 4; ++r) {
      long m = m0 + 16 * wave + q * 4 + r;
      int n = n0 + nt * 16 + l15;
      float v = acc[nt][r];
      if (bias) v += bias[n];
      if (act == 1) v = fmaxf(v, 0.f);
      else if (act == 2) v = softplus_(v);
      long o = m * (long)N + n;
      if (outf) outf[o] = v;
      if (outb) outb[o] = f2b(v);
    }
  }
}

// ---------------------------------------------------------------------------
// Sequential recurrence kernel. Grid = 8 WGs, block = 1024 (16 waves).
// WG g owns batch rows 16g..16g+15. Per step stages (barrier between):
//  S1: waves 8..15: enc_h (B-frags in regs);  waves 0..7: gates += h@lstm_rec
//  S2: waves 0..7: enc_mu/sigma -> z;         waves 8..15: gates += h@lstm_rec
//  S3: waves 8..15: z1 = relu(z@phi_z+b)
//  S4: all: gates += z1@lstm_kz; lane-local LSTM pointwise -> h,c
// Gate col ownership: wave w owns cols 16w..16w+15 of each of i/f/g/o.
// ---------------------------------------------------------------------------
__launch_bounds__(1024)
__global__ void seq_kernel(const float* __restrict__ eps,
                           const float* __restrict__ encx,
                           const float* __restrict__ lstmx,
                           const unsigned short* __restrict__ ench_p,
                           const unsigned short* __restrict__ mu_p,
                           const unsigned short* __restrict__ sig_p,
                           const unsigned short* __restrict__ phiz_p,
                           const unsigned short* __restrict__ kz_p,
                           const unsigned short* __restrict__ rec_p,
                           const float* __restrict__ mu_b,
                           const float* __restrict__ sig_b,
                           const float* __restrict__ phiz_b,
                           unsigned short* __restrict__ hprev,
                           unsigned short* __restrict__ z1g,
                           float* __restrict__ out0,
                           float* __restrict__ out_encmu,
                           float* __restrict__ out_encsig) {
  __shared__ unsigned short h_s[16][264];   // h (bf16), padded
  __shared__ unsigned short ehs[16][136];   // enc_h
  __shared__ unsigned short z_s[16][136];   // z
  __shared__ unsigned short z1_s[16][136];  // z1

  const int g = blockIdx.x;
  const int tid = threadIdx.x;
  const int wave = tid >> 6, lane = tid & 63, q = lane >> 4, l15 = lane & 15;

  // init h=0 in LDS; write hprev[t=0]=0 for our rows
  for (int i = tid; i < 16 * 264; i += 1024) ((unsigned short*)h_s)[i] = 0;
  for (int i = tid; i < 16 * 256; i += 1024) {
    int r = i >> 8, j = i & 255;
    hprev[((size_t)(16 * g + r) * 512) * 256 + j] = 0;
  }

  // persistent weight fragments in registers
  s8v fw[8];   // waves<8: enc_mu(4)+enc_sigma(4); waves>=8: enc_h_w h-part (8)
  s8v fp[4];   // phi_z (used by waves>=8)
  {
    if (wave < 8) {
      const int n0 = 16 * wave;
#pragma unroll
      for (int kt = 0; kt < 4; ++kt) {
        fw[kt]     = *(const s8v*)(mu_p  + ((((size_t)(kt * 4 + q)) * 128 + n0 + l15) << 3));
        fw[4 + kt] = *(const s8v*)(sig_p + ((((size_t)(kt * 4 + q)) * 128 + n0 + l15) << 3));
      }
    } else {
      const int n0 = 16 * (wave - 8);
#pragma unroll
      for (int kt = 0; kt < 8; ++kt)
        fw[kt] = *(const s8v*)(ench_p + ((((size_t)(kt * 4 + q)) * 128 + n0 + l15) << 3));
    }
    const int n0p = 16 * (wave & 7);
#pragma unroll
    for (int kt = 0; kt < 4; ++kt)
      fp[kt] = *(const s8v*)(phiz_p + ((((size_t)(kt * 4 + q)) * 128 + n0p + l15) << 3));
  }

  const int jz = 16 * (wave & 7) + l15;     // Z-dim col for enc/z stages
  const float mub = mu_b[jz], sgb = sig_b[jz], pzb = phiz_b[jz];
  float c_reg[4] = {0.f, 0.f, 0.f, 0.f};

  const int brow_base = 16 * g + q * 4;     // + r
  const int gcol = 16 * wave + l15;         // gate col within each 256-block

  __syncthreads();

  for (int t = 0; t < 512; ++t) {
    // gates accumulator, init with precomputed x-contribution (incl lstm_bias)
    f4v acc[4];
#pragma unroll
    for (int gb = 0; gb < 4; ++gb) {
#pragma unroll
      for (int r = 0; r < 4; ++r) {
        size_t m = (size_t)(brow_base + r) * 512 + t;
        acc[gb][r] = lstmx[m * 1024 + gb * 256 + gcol];
      }
    }

    // ---- S1 ----
    if (wave >= 8) {
      const int n0 = 16 * (wave - 8);
      f4v eh;
#pragma unroll
      for (int r = 0; r < 4; ++r) {
        size_t m = (size_t)(brow_base + r) * 512 + t;
        eh[r] = encx[m * 128 + n0 + l15];   // includes enc_h_b
      }
#pragma unroll
      for (int kt = 0; kt < 8; ++kt) {
        s8v a = *(const s8v*)&h_s[l15][kt * 32 + q * 8];
        eh = __builtin_amdgcn_mfma_f32_16x16x32_bf16(a, fw[kt], eh, 0, 0, 0);
      }
#pragma unroll
      for (int r = 0; r < 4; ++r)
        ehs[q * 4 + r][n0 + l15] = f2b(fmaxf(eh[r], 0.f));
    } else {
      // gates += h @ lstm_rec (this wave's cols)
#pragma unroll
      for (int kt = 0; kt < 8; ++kt) {
        s8v a = *(const s8v*)&h_s[l15][kt * 32 + q * 8];
#pragma unroll
        for (int gb = 0; gb < 4; ++gb) {
          const s8v b = *(const s8v*)(rec_p + ((((size_t)(kt * 4 + q)) * 1024 + gb * 256 + gcol) << 3));
          acc[gb] = __builtin_amdgcn_mfma_f32_16x16x32_bf16(a, b, acc[gb], 0, 0, 0);
        }
      }
    }
    __syncthreads();

    // ---- S2 ----
    if (wave < 8) {
      const int n0 = 16 * wave;
      f4v mu = (f4v){0.f, 0.f, 0.f, 0.f}, sg = (f4v){0.f, 0.f, 0.f, 0.f};
#pragma unroll
      for (int kt = 0; kt < 4; ++kt) {
        s8v a = *(const s8v*)&ehs[l15][kt * 32 + q * 8];
        mu = __builtin_amdgcn_mfma_f32_16x16x32_bf16(a, fw[kt], mu, 0, 0, 0);
        sg = __builtin_amdgcn_mfma_f32_16x16x32_bf16(a, fw[4 + kt], sg, 0, 0, 0);
      }
#pragma unroll
      for (int r = 0; r < 4; ++r) {
        size_t m = (size_t)(brow_base + r) * 512 + t;
        float mv = mu[r] + mub;
        float sv = softplus_(sg[r] + sgb);
        float ev = eps[m * 128 + n0 + l15];
        out_encmu[m * 128 + n0 + l15] = mv;
        out_encsig[m * 128 + n0 + l15] = sv;
        z_s[q * 4 + r][n0 + l15] = f2b(sv * ev + mv);
      }
    } else {
      // gates += h @ lstm_rec (this wave's cols)
#pragma unroll
      for (int kt = 0; kt < 8; ++kt) {
        s8v a = *(const s8v*)&h_s[l15][kt * 32 + q * 8];
#pragma unroll
        for (int gb = 0; gb < 4; ++gb) {
          const s8v b = *(const s8v*)(rec_p + ((((size_t)(kt * 4 + q)) * 1024 + gb * 256 + gcol) << 3));
          acc[gb] = __builtin_amdgcn_mfma_f32_16x16x32_bf16(a, b, acc[gb], 0, 0, 0);
        }
      }
    }
    __syncthreads();

    // ---- S3: z1 ----
    if (wave >= 8) {
      const int n0 = 16 * (wave - 8);
      f4v zz = (f4v){0.f, 0.f, 0.f, 0.f};
#pragma unroll
      for (int kt = 0; kt < 4; ++kt) {
        s8v a = *(const s8v*)&z_s[l15][kt * 32 + q * 8];
        zz = __builtin_amdgcn_mfma_f32_16x16x32_bf16(a, fp[kt], zz, 0, 0, 0);
      }
#pragma unroll
      for (int r = 0; r < 4; ++r) {
        size_t m = (size_t)(brow_base + r) * 512 + t;
        float v = fmaxf(zz[r] + pzb, 0.f);
        unsigned short bv = f2b(v);
        z1_s[q * 4 + r][n0 + l15] = bv;
        z1g[m * 128 + n0 + l15] = bv;
        if (t == 511) out0[(size_t)(brow_base + r) * 128 + n0 + l15] = v;
      }
    }
    __syncthreads();

    // ---- S4: gates += z1 @ lstm_kz, then lane-local LSTM pointwise ----
#pragma unroll
    for (int kt = 0; kt < 4; ++kt) {
      s8v a = *(const s8v*)&z1_s[l15][kt * 32 + q * 8];
#pragma unroll
      for (int gb = 0; gb < 4; ++gb) {
        const s8v b = *(const s8v*)(kz_p + ((((size_t)(kt * 4 + q)) * 1024 + gb * 256 + gcol) << 3));
        acc[gb] = __builtin_amdgcn_mfma_f32_16x16x32_bf16(a, b, acc[gb], 0, 0, 0);
      }
    }
#pragma unroll
    for (int r = 0; r < 4; ++r) {
      float iv = sigmoidf_(acc[0][r]);
      float fv = sigmoidf_(acc[1][r]);
      float gv = tanh_(acc[2][r]);
      float ov = sigmoidf_(acc[3][r]);
      float cn = fv * c_reg[r] + iv * gv;
      float hn = ov * tanh_(cn);
      c_reg[r] = cn;
      unsigned short hb = f2b(hn);
      h_s[q * 4 + r][gcol] = hb;
      if (t < 511)
        hprev[((size_t)(brow_base + r) * 512 + (t + 1)) * 256 + gcol] = hb;
    }
    __syncthreads();
  }
}

// ---------------------------------------------------------------------------
extern "C" void kernel_launch(void* const* d_in, const int* in_sizes, int n_in,
                              void* d_out, int out_size, void* d_ws, size_t ws_size,
                              hipStream_t stream) {
  const float* x        = (const float*)d_in[0];
  const float* eps      = (const float*)d_in[1];
  const float* prih_w   = (const float*)d_in[2];
  const float* prih_b   = (const float*)d_in[3];
  const float* primu_w  = (const float*)d_in[4];
  const float* primu_b  = (const float*)d_in[5];
  const float* prisg_w  = (const float*)d_in[6];
  const float* prisg_b  = (const float*)d_in[7];
  const float* phix_w   = (const float*)d_in[8];
  const float* phix_b   = (const float*)d_in[9];
  const float* ench_w   = (const float*)d_in[10];
  const float* ench_b   = (const float*)d_in[11];
  const float* encmu_w  = (const float*)d_in[12];
  const float* encmu_b  = (const float*)d_in[13];
  const float* encsg_w  = (const float*)d_in[14];
  const float* encsg_b  = (const float*)d_in[15];
  const float* phiz_w   = (const float*)d_in[16];
  const float* phiz_b   = (const float*)d_in[17];
  const float* dech_w   = (const float*)d_in[18];
  const float* dech_b   = (const float*)d_in[19];
  const float* decmu_w  = (const float*)d_in[20];
  const float* decmu_b  = (const float*)d_in[21];
  const float* decsg_w  = (const float*)d_in[22];
  const float* decsg_b  = (const float*)d_in[23];
  const float* lstm_k   = (const float*)d_in[24];
  const float* lstm_r   = (const float*)d_in[25];
  const float* lstm_b   = (const float*)d_in[26];

  float* out = (float*)d_out;
  const size_t M = 65536;  // B*T

  // ---- workspace layout (bytes) ----
  char* ws = (char*)d_ws;
  unsigned short* x1W     = (unsigned short*)(ws);                       // 16 MB
  unsigned short* hprevW  = (unsigned short*)(ws + 16777216);            // 32 MB
  unsigned short* z1gW    = (unsigned short*)(ws + 50331648);            // 16 MB
  unsigned short* priorhW = (unsigned short*)(ws + 67108864);            // 16 MB
  unsigned short* dechW   = (unsigned short*)(ws + 83886080);            // 16 MB
  float*          encxW   = (float*)(ws + 100663296);                    // 32 MB
  float*          lstmxW  = (float*)(ws + 134217728);                    // 256 MB
  unsigned short* packW   = (unsigned short*)(ws + 402653184);           // 1.5 MB

  // packed weight sub-offsets (ushort elements)
  unsigned short* phix_p  = packW + 0;
  unsigned short* encxp_p = packW + 16384;
  unsigned short* ench_p  = packW + 32768;
  unsigned short* mu_p    = packW + 65536;
  unsigned short* sig_p   = packW + 81920;
  unsigned short* phiz_p  = packW + 98304;
  unsigned short* kx_p    = packW + 114688;
  unsigned short* kz_p    = packW + 245760;
  unsigned short* rec_p   = packW + 376832;
  unsigned short* prih_p  = packW + 638976;
  unsigned short* primu_p = packW + 671744;
  unsigned short* prisg_p = packW + 688128;
  unsigned short* decz_p  = packW + 704512;
  unsigned short* dech_p  = packW + 720896;
  unsigned short* decmu_p = packW + 753664;
  unsigned short* decsg_p = packW + 770048;

  auto pack = [&](const float* src, unsigned short* dst, int K, int N) {
    int n = K * N;
    pack_b_kernel<<<dim3((n + 255) / 256), dim3(256), 0, stream>>>(src, dst, K, N);
  };
  pack(phix_w, phix_p, 128, 128);
  pack(ench_w, encxp_p, 128, 128);                 // enc_h_w rows 0..127 (x part)
  pack(ench_w + 128 * 128, ench_p, 256, 128);      // enc_h_w rows 128..383 (h part)
  pack(encmu_w, mu_p, 128, 128);
  pack(encsg_w, sig_p, 128, 128);
  pack(phiz_w, phiz_p, 128, 128);
  pack(lstm_k, kx_p, 128, 1024);                   // lstm_kernel rows 0..127 (x1)
  pack(lstm_k + 128 * 1024, kz_p, 128, 1024);      // rows 128..255 (z1)
  pack(lstm_r, rec_p, 256, 1024);
  pack(prih_w, prih_p, 256, 128);
  pack(primu_w, primu_p, 128, 128);
  pack(prisg_w, prisg_p, 128, 128);
  pack(dech_w, decz_p, 128, 128);                  // dec_h_w rows 0..127 (z1 part)
  pack(dech_w + 128 * 128, dech_p, 256, 128);      // rows 128..383 (h part)
  pack(decmu_w, decmu_p, 128, 128);
  pack(decsg_w, decsg_p, 128, 128);

  // output region offsets (floats)
  float* o_rnn   = out;                 // [128,128]
  float* o_encmu = out + 16384;
  float* o_encsg = out + 8404992;
  float* o_decmu = out + 16793600;
  float* o_decsg = out + 25182208;
  float* o_primu = out + 33570816;
  float* o_prisg = out + 41959424;

  dim3 blk(256);
  dim3 g128(2, 1024);    // N=128 GEMM grid
  dim3 g1024(16, 1024);  // N=1024 GEMM grid

  // PRE: x1 = x @ phi_x_w + b   (bf16 out)
  gemm64_kernel<<<g128, blk, 0, stream>>>(x, 1, 128, phix_p, 128,
                                          nullptr, 0, nullptr, 0,
                                          phix_b, 0, nullptr, x1W, 128);
  // encx = x1 @ enc_h_w[:F] + enc_h_b  (f32)
  gemm64_kernel<<<g128, blk, 0, stream>>>(x1W, 0, 128, encxp_p, 128,
                                          nullptr, 0, nullptr, 0,
                                          ench_b, 0, encxW, nullptr, 128);
  // lstmx = x1 @ lstm_kernel[:F] + lstm_bias  (f32)
  gemm64_kernel<<<g1024, blk, 0, stream>>>(x1W, 0, 128, kx_p, 128,
                                           nullptr, 0, nullptr, 0,
                                           lstm_b, 0, lstmxW, nullptr, 1024);

  // SEQ: the recurrence
  seq_kernel<<<dim3(8), dim3(1024), 0, stream>>>(eps, encxW, lstmxW,
                                                 ench_p, mu_p, sig_p, phiz_p, kz_p, rec_p,
                                                 encmu_b, encsg_b, phiz_b,
                                                 hprevW, z1gW,
                                                 o_rnn, o_encmu, o_encsg);

  // POST: prior head
  gemm64_kernel<<<g128, blk, 0, stream>>>(hprevW, 0, 256, prih_p, 256,
                                          nullptr, 0, nullptr, 0,
                                          prih_b, 1, nullptr, priorhW, 128);
  gemm64_kernel<<<g128, blk, 0, stream>>>(priorhW, 0, 128, primu_p, 128,
                                          nullptr, 0, nullptr, 0,
                                          primu_b, 0, o_primu, nullptr, 128);
  gemm64_kernel<<<g128, blk, 0, stream>>>(priorhW, 0, 128, prisg_p, 128,
                                          nullptr, 0, nullptr, 0,
                                          prisg_b, 2, o_prisg, nullptr, 128);
  // POST: dec head (dec_in = [z1, h])
  gemm64_kernel<<<g128, blk, 0, stream>>>(z1gW, 0, 128, decz_p, 128,
                                          hprevW, 256, dech_p, 256,
                                          dech_b, 1, nullptr, dechW, 128);
  gemm64_kernel<<<g128, blk, 0, stream>>>(dechW, 0, 128, decmu_p, 128,
                                          nullptr, 0, nullptr, 0,
                                          decmu_b, 0, o_decmu, nullptr, 128);
  gemm64_kernel<<<g128, blk, 0, stream>>>(dechW, 0, 128, decsg_p, 128,
                                          nullptr, 0, nullptr, 0,
                                          decsg_b, 2, o_decsg, nullptr, 128);

  (void)in_sizes; (void)n_in; (void)out_size; (void)ws_size;
}

// Round 2
// 5024.613 us; speedup vs baseline: 2.5885x; 2.5885x over previous
//
#include <hip/hip_runtime.h>
#include <stdint.h>
#include <stddef.h>

// ---------------------------------------------------------------------------
// VRNN: B=128, T=512, F=128, H=256, Z=128
// R2: seq kernel restructured to 32 WGs (8 groups x 4 parts, 512 thr each).
//  - ALL per-step weights live in registers (~176 VGPR/wave); zero weight
//    streaming in the T-loop (R1 re-read 768 KB/CU/step from L2).
//  - Group's 4 WGs each own 64 h-cols (gate cols j,256+j,512+j,768+j so the
//    LSTM pointwise is WG-local); enc chain replicated per WG; one h-exchange
//    per step via device-scope atomics (parts of a group land on one XCD via
//    blockIdx&7 grouping).
//  - lstmx precompute stored bf16 (halves traffic), prefetched 1 step ahead.
// ---------------------------------------------------------------------------

typedef short s8v __attribute__((ext_vector_type(8)));   // 8 x bf16 bits
typedef float f4v __attribute__((ext_vector_type(4)));

__device__ __forceinline__ unsigned short f2b(float x) {
  union { float f; unsigned int u; } v; v.f = x;
  unsigned int r = ((v.u >> 16) & 1u) + 0x7fffu;
  return (unsigned short)((v.u + r) >> 16);
}
__device__ __forceinline__ float b2f(unsigned short b) {
  union { unsigned int u; float f; } v; v.u = ((unsigned int)b) << 16;
  return v.f;
}
__device__ __forceinline__ float sigmoidf_(float x) { return 1.0f / (1.0f + __expf(-x)); }
__device__ __forceinline__ float tanh_(float x) { return 1.0f - 2.0f / (__expf(2.0f * x) + 1.0f); }
__device__ __forceinline__ float softplus_(float x) { return fmaxf(x, 0.0f) + log1pf(__expf(-fabsf(x))); }

// Pack a row-major [K,N] f32 weight matrix into bf16 MFMA-B-fragment layout:
// element (k,n) -> dst[ ((k>>3)*N + n)*8 + (k&7) ]
__global__ void pack_b_kernel(const float* __restrict__ src, unsigned short* __restrict__ dst,
                              int K, int N) {
  int idx = blockIdx.x * 256 + threadIdx.x;
  if (idx >= K * N) return;
  int k = idx / N, n = idx - k * N;
  dst[((((size_t)(k >> 3)) * N + n) << 3) + (k & 7)] = f2b(src[idx]);
}

// ---------------------------------------------------------------------------
// Generic tiled MFMA GEMM: C[M,N] = act( A1@B1 (+ A2@B2) + bias )
// ---------------------------------------------------------------------------
__launch_bounds__(256)
__global__ void gemm64_kernel(const void* __restrict__ A1, int a1_f32, int lda1,
                              const unsigned short* __restrict__ B1, int K1,
                              const void* __restrict__ A2, int lda2,
                              const unsigned short* __restrict__ B2, int K2,
                              const float* __restrict__ bias, int act,
                              float* __restrict__ outf, unsigned short* __restrict__ outb,
                              int N) {
  __shared__ unsigned short As[64][40];
  const int tid = threadIdx.x;
  const int wave = tid >> 6, lane = tid & 63, q = lane >> 4, l15 = lane & 15;
  const long m0 = (long)blockIdx.y * 64;
  const int n0 = blockIdx.x * 64;
  const int srow = tid >> 2, sc0 = (tid & 3) * 8;

  f4v acc[4];
#pragma unroll
  for (int i = 0; i < 4; ++i) acc[i] = (f4v){0.f, 0.f, 0.f, 0.f};

  for (int src = 0; src < 2; ++src) {
    const void* A = src ? A2 : A1;
    if (A == nullptr) continue;
    const unsigned short* Bp = src ? B2 : B1;
    const int K = src ? K2 : K1;
    const int lda = src ? lda2 : lda1;
    const int af32 = src ? 0 : a1_f32;
    const int nkc = K >> 5;
    for (int kc = 0; kc < nkc; ++kc) {
      {
        long aoff = (m0 + srow) * (long)lda + kc * 32 + sc0;
        if (af32) {
          const float* Ap = (const float*)A + aoff;
          float4 u0 = *(const float4*)(Ap);
          float4 u1 = *(const float4*)(Ap + 4);
          unsigned short* d = &As[srow][sc0];
          d[0] = f2b(u0.x); d[1] = f2b(u0.y); d[2] = f2b(u0.z); d[3] = f2b(u0.w);
          d[4] = f2b(u1.x); d[5] = f2b(u1.y); d[6] = f2b(u1.z); d[7] = f2b(u1.w);
        } else {
          const s8v* Ap = (const s8v*)((const unsigned short*)A + aoff);
          *(s8v*)&As[srow][sc0] = *Ap;
        }
      }
      __syncthreads();
      s8v a = *(const s8v*)&As[16 * wave + l15][q * 8];
#pragma unroll
      for (int nt = 0; nt < 4; ++nt) {
        const s8v b = *(const s8v*)(Bp + ((((long)kc * 4 + q) * N + n0 + nt * 16 + l15) << 3));
        acc[nt] = __builtin_amdgcn_mfma_f32_16x16x32_bf16(a, b, acc[nt], 0, 0, 0);
      }
      __syncthreads();
    }
  }
#pragma unroll
  for (int nt = 0; nt < 4; ++nt) {
#pragma unroll
    for (int r = 0; r < 4; ++r) {
      long m = m0 + 16 * wave + q * 4 + r;
      int n = n0 + nt * 16 + l15;
      float v = acc[nt][r];
      if (bias) v += bias[n];
      if (act == 1) v = fmaxf(v, 0.f);
      else if (act == 2) v = softplus_(v);
      long o = m * (long)N + n;
      if (outf) outf[o] = v;
      if (outb) outb[o] = f2b(v);
    }
  }
}

// ---------------------------------------------------------------------------
// Sequential recurrence. Grid = 32 WGs x 512 thr (8 waves).
// g = blockIdx&7 (batch rows 16g..16g+15), p = blockIdx>>3 (h-cols 64p..+63).
// Wave roles: j = wave&3 -> h-col tile 64p+16j..+15; half = wave>>2:
//   half 0 -> gate blocks {0(i), 2(g)};  half 1 -> {1(f), 3(o)}.
// All 8 waves also run the enc chain for enc cols 16*wave..+15 (replicated
// across the group's 4 WGs; avoids a second exchange).
// Per-step h exchange: own 64-col slice -> hx[g][t&1] (agent-scope atomics),
// counter cnt[g][t], poll to 4, read back full 256-col h.
// ---------------------------------------------------------------------------
__launch_bounds__(512, 2)
__global__ void seq_kernel(const float* __restrict__ eps,
                           const float* __restrict__ encx,
                           const unsigned short* __restrict__ lstmx,
                           const unsigned short* __restrict__ ench_p,
                           const unsigned short* __restrict__ mu_p,
                           const unsigned short* __restrict__ sig_p,
                           const unsigned short* __restrict__ phiz_p,
                           const unsigned short* __restrict__ kz_p,
                           const unsigned short* __restrict__ rec_p,
                           const float* __restrict__ mu_b,
                           const float* __restrict__ sig_b,
                           const float* __restrict__ phiz_b,
                           unsigned short* __restrict__ hprev,
                           unsigned short* __restrict__ z1g,
                           float* __restrict__ out0,
                           float* __restrict__ out_encmu,
                           float* __restrict__ out_encsig,
                           unsigned int* __restrict__ hx,
                           unsigned int* __restrict__ cnt) {
  __shared__ unsigned short h_s[16][264];
  __shared__ unsigned short ehs[16][136];
  __shared__ unsigned short z_s[16][136];
  __shared__ unsigned short z1_s[16][136];
  __shared__ float u_s[16][68];

  const int g = blockIdx.x & 7, p = blockIdx.x >> 3;
  const int tid = threadIdx.x;
  const int wave = tid >> 6, lane = tid & 63, q = lane >> 4, l15 = lane & 15;
  const int j = wave & 3, half = wave >> 2;
  const int ec0 = 16 * wave;                 // enc col tile
  const int hcol = 64 * p + 16 * j + l15;    // owned h-col (gate duty)

  // zero h_s; zero hprev[t=0] (one part per group does it)
  for (int i = tid; i < 16 * 264; i += 512) ((unsigned short*)h_s)[i] = 0;
  if (p == 0) {
    for (int i = tid; i < 16 * 256; i += 512) {
      int r = i >> 8, cc = i & 255;
      hprev[((size_t)(16 * g + r) * 512) * 256 + cc] = 0;
    }
  }

  // ---- persistent register weights ----
  s8v rec_f[8][2], kz_f[4][2], ench_f[8], muf[4], sgf[4], pzf[4];
#pragma unroll
  for (int kt = 0; kt < 8; ++kt) {
#pragma unroll
    for (int u = 0; u < 2; ++u) {
      int gc = (half + 2 * u) * 256 + hcol;
      rec_f[kt][u] = *(const s8v*)(rec_p + ((((size_t)(kt * 4 + q)) * 1024 + gc) << 3));
    }
    ench_f[kt] = *(const s8v*)(ench_p + ((((size_t)(kt * 4 + q)) * 128 + ec0 + l15) << 3));
  }
#pragma unroll
  for (int kt = 0; kt < 4; ++kt) {
#pragma unroll
    for (int u = 0; u < 2; ++u) {
      int gc = (half + 2 * u) * 256 + hcol;
      kz_f[kt][u] = *(const s8v*)(kz_p + ((((size_t)(kt * 4 + q)) * 1024 + gc) << 3));
    }
    muf[kt] = *(const s8v*)(mu_p  + ((((size_t)(kt * 4 + q)) * 128 + ec0 + l15) << 3));
    sgf[kt] = *(const s8v*)(sig_p + ((((size_t)(kt * 4 + q)) * 128 + ec0 + l15) << 3));
    pzf[kt] = *(const s8v*)(phiz_p + ((((size_t)(kt * 4 + q)) * 128 + ec0 + l15) << 3));
  }

  const float mub = mu_b[ec0 + l15], sgb = sig_b[ec0 + l15], pzb = phiz_b[ec0 + l15];
  float c_reg[4] = {0.f, 0.f, 0.f, 0.f};
  const int brow = 16 * g + q * 4;           // + r

  // ---- prefetch t=0 ----
  unsigned short pf_l[8];
  float pf_e[4], pf_p[4];
#pragma unroll
  for (int r = 0; r < 4; ++r) {
    size_t m = (size_t)(brow + r) * 512;
#pragma unroll
    for (int u = 0; u < 2; ++u)
      pf_l[u * 4 + r] = lstmx[m * 1024 + (half + 2 * u) * 256 + hcol];
    pf_e[r] = encx[m * 128 + ec0 + l15];
    pf_p[r] = eps[m * 128 + ec0 + l15];
  }

  __syncthreads();

  for (int t = 0; t < 512; ++t) {
    // consume prefetch
    f4v acc0, acc1, eh;
    float epsv[4];
#pragma unroll
    for (int r = 0; r < 4; ++r) {
      acc0[r] = b2f(pf_l[r]);
      acc1[r] = b2f(pf_l[4 + r]);
      eh[r] = pf_e[r];
      epsv[r] = pf_p[r];
    }
    // issue prefetch for t+1
    {
      int tn = (t < 511) ? t + 1 : 511;
#pragma unroll
      for (int r = 0; r < 4; ++r) {
        size_t m = (size_t)(brow + r) * 512 + tn;
#pragma unroll
        for (int u = 0; u < 2; ++u)
          pf_l[u * 4 + r] = lstmx[m * 1024 + (half + 2 * u) * 256 + hcol];
        pf_e[r] = encx[m * 128 + ec0 + l15];
        pf_p[r] = eps[m * 128 + ec0 + l15];
      }
    }

    // ---- Stage A: enc_h + rec gates (A-frags from h_s, weights in regs) ----
#pragma unroll
    for (int kt = 0; kt < 8; ++kt) {
      s8v a = *(const s8v*)&h_s[l15][kt * 32 + q * 8];
      eh   = __builtin_amdgcn_mfma_f32_16x16x32_bf16(a, ench_f[kt], eh, 0, 0, 0);
      acc0 = __builtin_amdgcn_mfma_f32_16x16x32_bf16(a, rec_f[kt][0], acc0, 0, 0, 0);
      acc1 = __builtin_amdgcn_mfma_f32_16x16x32_bf16(a, rec_f[kt][1], acc1, 0, 0, 0);
    }
#pragma unroll
    for (int r = 0; r < 4; ++r)
      ehs[q * 4 + r][ec0 + l15] = f2b(fmaxf(eh[r], 0.f));
    __syncthreads();

    // ---- Stage B: enc_mu / enc_sigma -> z ----
    {
      f4v mu = (f4v){0.f, 0.f, 0.f, 0.f}, sg = (f4v){0.f, 0.f, 0.f, 0.f};
#pragma unroll
      for (int kt = 0; kt < 4; ++kt) {
        s8v a = *(const s8v*)&ehs[l15][kt * 32 + q * 8];
        mu = __builtin_amdgcn_mfma_f32_16x16x32_bf16(a, muf[kt], mu, 0, 0, 0);
        sg = __builtin_amdgcn_mfma_f32_16x16x32_bf16(a, sgf[kt], sg, 0, 0, 0);
      }
#pragma unroll
      for (int r = 0; r < 4; ++r) {
        size_t m = (size_t)(brow + r) * 512 + t;
        float mv = mu[r] + mub;
        float sv = softplus_(sg[r] + sgb);
        out_encmu[m * 128 + ec0 + l15] = mv;
        out_encsig[m * 128 + ec0 + l15] = sv;
        z_s[q * 4 + r][ec0 + l15] = f2b(sv * epsv[r] + mv);
      }
    }
    __syncthreads();

    // ---- Stage C: z1 = relu(z @ phi_z + b) ----
    {
      f4v zz = (f4v){0.f, 0.f, 0.f, 0.f};
#pragma unroll
      for (int kt = 0; kt < 4; ++kt) {
        s8v a = *(const s8v*)&z_s[l15][kt * 32 + q * 8];
        zz = __builtin_amdgcn_mfma_f32_16x16x32_bf16(a, pzf[kt], zz, 0, 0, 0);
      }
#pragma unroll
      for (int r = 0; r < 4; ++r) {
        size_t m = (size_t)(brow + r) * 512 + t;
        float v = fmaxf(zz[r] + pzb, 0.f);
        unsigned short bv = f2b(v);
        z1_s[q * 4 + r][ec0 + l15] = bv;
        z1g[m * 128 + ec0 + l15] = bv;
        if (t == 511) out0[(size_t)(brow + r) * 128 + ec0 + l15] = v;
      }
    }
    __syncthreads();

    // ---- Stage D: kz gates + LSTM pointwise ----
#pragma unroll
    for (int kt = 0; kt < 4; ++kt) {
      s8v a = *(const s8v*)&z1_s[l15][kt * 32 + q * 8];
      acc0 = __builtin_amdgcn_mfma_f32_16x16x32_bf16(a, kz_f[kt][0], acc0, 0, 0, 0);
      acc1 = __builtin_amdgcn_mfma_f32_16x16x32_bf16(a, kz_f[kt][1], acc1, 0, 0, 0);
    }
    if (half == 0) {
      // acc0 = i, acc1 = g : u = sigmoid(i)*tanh(g)
#pragma unroll
      for (int r = 0; r < 4; ++r)
        u_s[q * 4 + r][16 * j + l15] = sigmoidf_(acc0[r]) * tanh_(acc1[r]);
    }
    __syncthreads();
    if (half == 1) {
      // acc0 = f, acc1 = o
#pragma unroll
      for (int r = 0; r < 4; ++r) {
        float cn = sigmoidf_(acc0[r]) * c_reg[r] + u_s[q * 4 + r][16 * j + l15];
        float hn = sigmoidf_(acc1[r]) * tanh_(cn);
        c_reg[r] = cn;
        unsigned short hb = f2b(hn);
        h_s[q * 4 + r][hcol] = hb;
        if (t < 511)
          hprev[((size_t)(brow + r) * 512 + (t + 1)) * 256 + hcol] = hb;
      }
    }
    __syncthreads();

    if (t < 511) {
      const int slot = t & 1;
      // repack own 64-col slice -> hx (1 dword atomic store per thread)
      {
        int row = tid >> 5, dw = tid & 31;
        unsigned int v = *(const unsigned int*)&h_s[row][64 * p + 2 * dw];
        __hip_atomic_store(&hx[(((g * 2 + slot) * 16 + row) << 7) + (p << 5) + dw], v,
                           __ATOMIC_RELAXED, __HIP_MEMORY_SCOPE_AGENT);
      }
      __syncthreads();   // drains the stores (vmcnt(0) before barrier)
      if (tid == 0) {
        __hip_atomic_fetch_add(&cnt[(g << 9) + t], 1, __ATOMIC_RELEASE, __HIP_MEMORY_SCOPE_AGENT);
        while (__hip_atomic_load(&cnt[(g << 9) + t], __ATOMIC_ACQUIRE, __HIP_MEMORY_SCOPE_AGENT) < 4)
          __builtin_amdgcn_s_sleep(2);
      }
      __syncthreads();
      // read full h (4 dword atomic loads per thread) -> h_s
#pragma unroll
      for (int k = 0; k < 4; ++k) {
        int idx = tid + k * 512;
        int row = idx >> 7, dw = idx & 127;
        unsigned int v = __hip_atomic_load(&hx[(((g * 2 + slot) * 16 + row) << 7) + dw],
                                           __ATOMIC_RELAXED, __HIP_MEMORY_SCOPE_AGENT);
        *(unsigned int*)&h_s[row][2 * dw] = v;
      }
      __syncthreads();
    }
  }
}

// ---------------------------------------------------------------------------
extern "C" void kernel_launch(void* const* d_in, const int* in_sizes, int n_in,
                              void* d_out, int out_size, void* d_ws, size_t ws_size,
                              hipStream_t stream) {
  const float* x        = (const float*)d_in[0];
  const float* eps      = (const float*)d_in[1];
  const float* prih_w   = (const float*)d_in[2];
  const float* prih_b   = (const float*)d_in[3];
  const float* primu_w  = (const float*)d_in[4];
  const float* primu_b  = (const float*)d_in[5];
  const float* prisg_w  = (const float*)d_in[6];
  const float* prisg_b  = (const float*)d_in[7];
  const float* phix_w   = (const float*)d_in[8];
  const float* phix_b   = (const float*)d_in[9];
  const float* ench_w   = (const float*)d_in[10];
  const float* ench_b   = (const float*)d_in[11];
  const float* encmu_w  = (const float*)d_in[12];
  const float* encmu_b  = (const float*)d_in[13];
  const float* encsg_w  = (const float*)d_in[14];
  const float* encsg_b  = (const float*)d_in[15];
  const float* phiz_w   = (const float*)d_in[16];
  const float* phiz_b   = (const float*)d_in[17];
  const float* dech_w   = (const float*)d_in[18];
  const float* dech_b   = (const float*)d_in[19];
  const float* decmu_w  = (const float*)d_in[20];
  const float* decmu_b  = (const float*)d_in[21];
  const float* decsg_w  = (const float*)d_in[22];
  const float* decsg_b  = (const float*)d_in[23];
  const float* lstm_k   = (const float*)d_in[24];
  const float* lstm_r   = (const float*)d_in[25];
  const float* lstm_b   = (const float*)d_in[26];

  float* out = (float*)d_out;

  // ---- workspace layout (bytes) ----
  char* ws = (char*)d_ws;
  unsigned short* x1W     = (unsigned short*)(ws);                       // 16 MB
  unsigned short* hprevW  = (unsigned short*)(ws + 16777216);            // 32 MB
  unsigned short* z1gW    = (unsigned short*)(ws + 50331648);            // 16 MB
  unsigned short* priorhW = (unsigned short*)(ws + 67108864);            // 16 MB
  unsigned short* dechW   = (unsigned short*)(ws + 83886080);            // 16 MB
  float*          encxW   = (float*)(ws + 100663296);                    // 32 MB
  unsigned short* lstmxW  = (unsigned short*)(ws + 134217728);           // 128 MB (bf16)
  unsigned short* packW   = (unsigned short*)(ws + 268435456);           // ~1.6 MB
  unsigned int*   hxW     = (unsigned int*)(ws + 272629760);             // 128 KB
  unsigned int*   cntW    = (unsigned int*)(ws + 272760832);             // 16 KB

  // packed weight sub-offsets (ushort elements)
  unsigned short* phix_p  = packW + 0;
  unsigned short* encxp_p = packW + 16384;
  unsigned short* ench_p  = packW + 32768;
  unsigned short* mu_p    = packW + 65536;
  unsigned short* sig_p   = packW + 81920;
  unsigned short* phiz_p  = packW + 98304;
  unsigned short* kx_p    = packW + 114688;
  unsigned short* kz_p    = packW + 245760;
  unsigned short* rec_p   = packW + 376832;
  unsigned short* prih_p  = packW + 638976;
  unsigned short* primu_p = packW + 671744;
  unsigned short* prisg_p = packW + 688128;
  unsigned short* decz_p  = packW + 704512;
  unsigned short* dech_p  = packW + 720896;
  unsigned short* decmu_p = packW + 753664;
  unsigned short* decsg_p = packW + 770048;

  auto pack = [&](const float* src, unsigned short* dst, int K, int N) {
    int n = K * N;
    pack_b_kernel<<<dim3((n + 255) / 256), dim3(256), 0, stream>>>(src, dst, K, N);
  };
  pack(phix_w, phix_p, 128, 128);
  pack(ench_w, encxp_p, 128, 128);
  pack(ench_w + 128 * 128, ench_p, 256, 128);
  pack(encmu_w, mu_p, 128, 128);
  pack(encsg_w, sig_p, 128, 128);
  pack(phiz_w, phiz_p, 128, 128);
  pack(lstm_k, kx_p, 128, 1024);
  pack(lstm_k + 128 * 1024, kz_p, 128, 1024);
  pack(lstm_r, rec_p, 256, 1024);
  pack(prih_w, prih_p, 256, 128);
  pack(primu_w, primu_p, 128, 128);
  pack(prisg_w, prisg_p, 128, 128);
  pack(dech_w, decz_p, 128, 128);
  pack(dech_w + 128 * 128, dech_p, 256, 128);
  pack(decmu_w, decmu_p, 128, 128);
  pack(decsg_w, decsg_p, 128, 128);

  hipMemsetAsync(cntW, 0, 8 * 512 * 4, stream);

  // output region offsets (floats)
  float* o_rnn   = out;
  float* o_encmu = out + 16384;
  float* o_encsg = out + 8404992;
  float* o_decmu = out + 16793600;
  float* o_decsg = out + 25182208;
  float* o_primu = out + 33570816;
  float* o_prisg = out + 41959424;

  dim3 blk(256);
  dim3 g128(2, 1024);
  dim3 g1024(16, 1024);

  // PRE
  gemm64_kernel<<<g128, blk, 0, stream>>>(x, 1, 128, phix_p, 128,
                                          nullptr, 0, nullptr, 0,
                                          phix_b, 0, nullptr, x1W, 128);
  gemm64_kernel<<<g128, blk, 0, stream>>>(x1W, 0, 128, encxp_p, 128,
                                          nullptr, 0, nullptr, 0,
                                          ench_b, 0, encxW, nullptr, 128);
  gemm64_kernel<<<g1024, blk, 0, stream>>>(x1W, 0, 128, kx_p, 128,
                                           nullptr, 0, nullptr, 0,
                                           lstm_b, 0, nullptr, lstmxW, 1024);

  // SEQ
  seq_kernel<<<dim3(32), dim3(512), 0, stream>>>(eps, encxW, lstmxW,
                                                 ench_p, mu_p, sig_p, phiz_p, kz_p, rec_p,
                                                 encmu_b, encsg_b, phiz_b,
                                                 hprevW, z1gW,
                                                 o_rnn, o_encmu, o_encsg,
                                                 hxW, cntW);

  // POST: prior head
  gemm64_kernel<<<g128, blk, 0, stream>>>(hprevW, 0, 256, prih_p, 256,
                                          nullptr, 0, nullptr, 0,
                                          prih_b, 1, nullptr, priorhW, 128);
  gemm64_kernel<<<g128, blk, 0, stream>>>(priorhW, 0, 128, primu_p, 128,
                                          nullptr, 0, nullptr, 0,
                                          primu_b, 0, o_primu, nullptr, 128);
  gemm64_kernel<<<g128, blk, 0, stream>>>(priorhW, 0, 128, prisg_p, 128,
                                          nullptr, 0, nullptr, 0,
                                          prisg_b, 2, o_prisg, nullptr, 128);
  // POST: dec head
  gemm64_kernel<<<g128, blk, 0, stream>>>(z1gW, 0, 128, decz_p, 128,
                                          hprevW, 256, dech_p, 256,
                                          dech_b, 1, nullptr, dechW, 128);
  gemm64_kernel<<<g128, blk, 0, stream>>>(dechW, 0, 128, decmu_p, 128,
                                          nullptr, 0, nullptr, 0,
                                          decmu_b, 0, o_decmu, nullptr, 128);
  gemm64_kernel<<<g128, blk, 0, stream>>>(dechW, 0, 128, decsg_p, 128,
                                          nullptr, 0, nullptr, 0,
                                          decsg_b, 2, o_decsg, nullptr, 128);

  (void)in_sizes; (void)n_in; (void)out_size; (void)ws_size;
}